// Round 1
// baseline (122.432 us; speedup 1.0000x reference)
//
#include <hip/hip_runtime.h>
#include <math.h>

#define Bv 4
#define Nv 512
#define Dv 128
#define BND (Bv*Nv*Dv)      // 262144
#define NN  (Nv*Nv)         // 262144
#define EPSv 1e-9f

// -------------------------------------------------------------------------
// K1: A = softmax((edge_logits + gumbel(u))/TAU, axis=-1); write B copies to
// the A region of d_out. One block per row (512 rows), 256 threads, 2 cols
// per thread. Wave shfl reduce + 4-entry LDS combine.
// -------------------------------------------------------------------------
__global__ __launch_bounds__(256) void k_gumbel_softmax(
    const float* __restrict__ edge_logits,
    const float* __restrict__ u_noise,
    float* __restrict__ A_out)
{
    __shared__ float sred[4];
    const int row = blockIdx.x;
    const int t = threadIdx.x;

    const float u0 = u_noise[row*Nv + t];
    const float u1 = u_noise[row*Nv + t + 256];
    const float g0 = -logf(-logf(u0 + EPSv) + EPSv);
    const float g1 = -logf(-logf(u1 + EPSv) + EPSv);
    const float z0 = (edge_logits[row*Nv + t]       + g0) * 2.0f;  // 1/TAU = 2
    const float z1 = (edge_logits[row*Nv + t + 256] + g1) * 2.0f;

    // row max
    float m = fmaxf(z0, z1);
    #pragma unroll
    for (int off = 32; off >= 1; off >>= 1)
        m = fmaxf(m, __shfl_xor(m, off, 64));
    if ((t & 63) == 0) sred[t >> 6] = m;
    __syncthreads();
    m = fmaxf(fmaxf(sred[0], sred[1]), fmaxf(sred[2], sred[3]));

    const float e0 = expf(z0 - m);
    const float e1 = expf(z1 - m);
    float ssum = e0 + e1;
    #pragma unroll
    for (int off = 32; off >= 1; off >>= 1)
        ssum += __shfl_xor(ssum, off, 64);
    __syncthreads();            // sred reuse
    if ((t & 63) == 0) sred[t >> 6] = ssum;
    __syncthreads();
    const float inv = 1.0f / (sred[0] + sred[1] + sred[2] + sred[3]);

    const float a0 = e0 * inv;
    const float a1 = e1 * inv;
    #pragma unroll
    for (int bb = 0; bb < Bv; ++bb) {
        A_out[bb*NN + row*Nv + t]       = a0;
        A_out[bb*NN + row*Nv + t + 256] = a1;
    }
}

// -------------------------------------------------------------------------
// K2: proj = ES@Wp + bp (kept in LDS), then s' = proj@W1_src + b1,
//     t = proj@W1_tgt. 8 rows per block, 256 threads: thread -> (col c,
//     row-group rg), 4 rows each. LDS row reads are wave-broadcast (free).
// -------------------------------------------------------------------------
__global__ __launch_bounds__(256) void k_proj_st(
    const float* __restrict__ ES, const float* __restrict__ Wp,
    const float* __restrict__ bp, const float* __restrict__ W1,
    const float* __restrict__ b1,
    float* __restrict__ s_out, float* __restrict__ t_out)
{
    __shared__ float es[8][Dv];
    __shared__ float pr[8][Dv];
    const int row0 = blockIdx.x * 8;
    const int t = threadIdx.x;
    const int c  = t & 127;
    const int rg = t >> 7;          // 0..1 -> rows rg*4 .. rg*4+3

    for (int idx = t; idx < 8*Dv; idx += 256)
        es[idx >> 7][idx & 127] = ES[(row0 + (idx >> 7))*Dv + (idx & 127)];
    __syncthreads();

    // phase 1: proj
    {
        float acc[4];
        const float bpc = bp[c];
        #pragma unroll
        for (int r = 0; r < 4; ++r) acc[r] = bpc;
        for (int k = 0; k < Dv; ++k) {
            const float w = Wp[k*Dv + c];
            #pragma unroll
            for (int r = 0; r < 4; ++r)
                acc[r] = fmaf(es[rg*4 + r][k], w, acc[r]);
        }
        #pragma unroll
        for (int r = 0; r < 4; ++r) pr[rg*4 + r][c] = acc[r];
    }
    __syncthreads();

    // phase 2: s' and t in one k-loop
    float sacc[4], tacc[4];
    const float b1c = b1[c];
    #pragma unroll
    for (int r = 0; r < 4; ++r) { sacc[r] = b1c; tacc[r] = 0.0f; }
    for (int k = 0; k < Dv; ++k) {
        const float ws_ = W1[k*Dv + c];          // W1_src row k
        const float wt_ = W1[(Dv + k)*Dv + c];   // W1_tgt row k
        #pragma unroll
        for (int r = 0; r < 4; ++r) {
            const float pv = pr[rg*4 + r][k];
            sacc[r] = fmaf(pv, ws_, sacc[r]);
            tacc[r] = fmaf(pv, wt_, tacc[r]);
        }
    }
    #pragma unroll
    for (int r = 0; r < 4; ++r) {
        const int row = row0 + rg*4 + r;
        s_out[row*Dv + c] = sacc[r];
        t_out[row*Dv + c] = tacc[r];
    }
}

// -------------------------------------------------------------------------
// K3 (the hot kernel): hsum[b,i,d] = sum_j A[i,j]*relu(s'[b,j,d] + t[b,i,d]).
// Block = (b, 4 i's), 256 threads: d = t&127, group g = t>>7 handles 2 i's.
// s' tile (64 rows x 128) staged in LDS (32 KB). A index is wave-uniform
// (readfirstlane) -> scalar loads on the SALU pipe.
// Inner loop per j per thread: 1 LDS read + 2x(add,max,fma) = 6 VALU.
// -------------------------------------------------------------------------
__global__ __launch_bounds__(256) void k_aggregate(
    const float* __restrict__ s_buf, const float* __restrict__ t_buf,
    const float* __restrict__ A, float* __restrict__ hsum)
{
    const int JT = 64;
    __shared__ float sj[JT][Dv];    // 32 KB
    const int b  = blockIdx.y;
    const int i0 = blockIdx.x * 4;
    const int t  = threadIdx.x;
    const int d  = t & 127;
    const int g  = __builtin_amdgcn_readfirstlane(t >> 7);  // wave-uniform 0/1
    const int ia = i0 + g*2;
    const int ib = ia + 1;

    const float tv0 = t_buf[(b*Nv + ia)*Dv + d];
    const float tv1 = t_buf[(b*Nv + ib)*Dv + d];
    const float* __restrict__ Ar0 = A + ia*Nv;
    const float* __restrict__ Ar1 = A + ib*Nv;

    float acc0 = 0.0f, acc1 = 0.0f;
    for (int jt = 0; jt < Nv; jt += JT) {
        __syncthreads();
        const float4* __restrict__ src = (const float4*)(s_buf + (b*Nv + jt)*Dv);
        float4* dst = (float4*)(&sj[0][0]);
        #pragma unroll
        for (int u = 0; u < 8; ++u)
            dst[t + u*256] = src[t + u*256];
        __syncthreads();
        #pragma unroll 4
        for (int j = 0; j < JT; ++j) {
            const float a0 = Ar0[jt + j];
            const float a1 = Ar1[jt + j];
            const float sv = sj[j][d];
            acc0 = fmaf(a0, fmaxf(sv + tv0, 0.0f), acc0);
            acc1 = fmaf(a1, fmaxf(sv + tv1, 0.0f), acc1);
        }
    }
    hsum[(b*Nv + ia)*Dv + d] = acc0;
    hsum[(b*Nv + ib)*Dv + d] = acc1;
}

// -------------------------------------------------------------------------
// K4: next_state = ES + hsum@W2 + b2. Same mini-GEMM shape as K2.
// (b2 enters with coefficient sum_j A[i,j] == 1 exactly.)
// -------------------------------------------------------------------------
__global__ __launch_bounds__(256) void k_final(
    const float* __restrict__ ES, const float* __restrict__ hsum,
    const float* __restrict__ W2, const float* __restrict__ b2,
    float* __restrict__ out)
{
    __shared__ float hs[8][Dv];
    const int row0 = blockIdx.x * 8;
    const int t = threadIdx.x;
    const int c  = t & 127;
    const int rg = t >> 7;

    for (int idx = t; idx < 8*Dv; idx += 256)
        hs[idx >> 7][idx & 127] = hsum[(row0 + (idx >> 7))*Dv + (idx & 127)];
    __syncthreads();

    float acc[4];
    const float b2c = b2[c];
    #pragma unroll
    for (int r = 0; r < 4; ++r) acc[r] = b2c;
    for (int k = 0; k < Dv; ++k) {
        const float w = W2[k*Dv + c];
        #pragma unroll
        for (int r = 0; r < 4; ++r)
            acc[r] = fmaf(hs[rg*4 + r][k], w, acc[r]);
    }
    #pragma unroll
    for (int r = 0; r < 4; ++r) {
        const int row = row0 + rg*4 + r;
        out[row*Dv + c] = ES[row*Dv + c] + acc[r];
    }
}

extern "C" void kernel_launch(void* const* d_in, const int* in_sizes, int n_in,
                              void* d_out, int out_size, void* d_ws, size_t ws_size,
                              hipStream_t stream) {
    (void)in_sizes; (void)n_in; (void)out_size; (void)ws_size;
    const float* ES = (const float*)d_in[0];
    const float* Wp = (const float*)d_in[1];
    const float* bp = (const float*)d_in[2];
    const float* EL = (const float*)d_in[3];
    const float* W1 = (const float*)d_in[4];
    const float* b1 = (const float*)d_in[5];
    const float* W2 = (const float*)d_in[6];
    const float* b2 = (const float*)d_in[7];
    const float* UN = (const float*)d_in[8];

    float* out   = (float*)d_out;
    float* A_out = out + BND;            // A broadcast region: B*N*N floats

    float* s_buf = (float*)d_ws;         // s' = proj@W1_src + b1  (B*N*D)
    float* t_buf = s_buf + BND;          // t  = proj@W1_tgt       (B*N*D)
    float* h_buf = t_buf + BND;          // hsum                   (B*N*D)

    k_gumbel_softmax<<<Nv, 256, 0, stream>>>(EL, UN, A_out);
    k_proj_st<<<(Bv*Nv)/8, 256, 0, stream>>>(ES, Wp, bp, W1, b1, s_buf, t_buf);
    k_aggregate<<<dim3(Nv/4, Bv), 256, 0, stream>>>(s_buf, t_buf, A_out, h_buf);
    k_final<<<(Bv*Nv)/8, 256, 0, stream>>>(ES, h_buf, W2, b2, out);
}

// Round 2
// 110.630 us; speedup vs baseline: 1.1067x; 1.1067x over previous
//
#include <hip/hip_runtime.h>
#include <math.h>

#define Bv 4
#define Nv 512
#define Dv 128
#define BND (Bv*Nv*Dv)      // 262144
#define NN  (Nv*Nv)         // 262144
#define EPSv 1e-9f

// -------------------------------------------------------------------------
// k_prep: proj = ES@Wp + bp (LDS), then s' = proj@W1_src + b1,
//         t = proj@W1_tgt. 8 rows/block, grid 256. Unrolled k-loops so the
//         W-loads pipeline (1 wave/SIMD -> ILP must hide the ~200cyc L2 lat).
// -------------------------------------------------------------------------
__global__ __launch_bounds__(256) void k_prep(
    const float* __restrict__ ES, const float* __restrict__ Wp,
    const float* __restrict__ bp, const float* __restrict__ W1,
    const float* __restrict__ b1,
    float* __restrict__ s_out, float* __restrict__ t_out)
{
    __shared__ float es[8][Dv];
    __shared__ float pr[8][Dv];
    const int row0 = blockIdx.x * 8;
    const int t = threadIdx.x;
    const int c  = t & 127;
    const int rg = t >> 7;          // 0..1 -> rows rg*4 .. rg*4+3

    for (int idx = t; idx < 8*Dv; idx += 256)
        es[idx >> 7][idx & 127] = ES[(row0 + (idx >> 7))*Dv + (idx & 127)];
    __syncthreads();

    // phase 1: proj
    {
        float acc[4];
        const float bpc = bp[c];
        #pragma unroll
        for (int r = 0; r < 4; ++r) acc[r] = bpc;
        #pragma unroll 8
        for (int k = 0; k < Dv; ++k) {
            const float w = Wp[k*Dv + c];
            #pragma unroll
            for (int r = 0; r < 4; ++r)
                acc[r] = fmaf(es[rg*4 + r][k], w, acc[r]);
        }
        #pragma unroll
        for (int r = 0; r < 4; ++r) pr[rg*4 + r][c] = acc[r];
    }
    __syncthreads();

    // phase 2: s' and t in one k-loop
    float sacc[4], tacc[4];
    const float b1c = b1[c];
    #pragma unroll
    for (int r = 0; r < 4; ++r) { sacc[r] = b1c; tacc[r] = 0.0f; }
    #pragma unroll 8
    for (int k = 0; k < Dv; ++k) {
        const float ws_ = W1[k*Dv + c];          // W1_src row k
        const float wt_ = W1[(Dv + k)*Dv + c];   // W1_tgt row k
        #pragma unroll
        for (int r = 0; r < 4; ++r) {
            const float pv = pr[rg*4 + r][k];
            sacc[r] = fmaf(pv, ws_, sacc[r]);
            tacc[r] = fmaf(pv, wt_, tacc[r]);
        }
    }
    #pragma unroll
    for (int r = 0; r < 4; ++r) {
        const int row = row0 + rg*4 + r;
        s_out[row*Dv + c] = sacc[r];
        t_out[row*Dv + c] = tacc[r];
    }
}

// -------------------------------------------------------------------------
// k_main: block = (4 i-rows, batch b), 256 threads.
//   phase 0: gumbel-softmax for the 4 A-rows (1 wave/row, shfl reduce);
//            A -> LDS (reused by all 4 b-duplicates' j-loops) + this block's
//            b-copy of the A output.
//   phase 1: hsum[i,d] = sum_j A[i,j]*relu(s'[b,j,d]+t[b,i,d]) with s'
//            staged in 64x128 LDS tiles. A reads are wave-uniform LDS
//            broadcasts (x4-unroll -> ds_read_b128).
//   phase 2: out = ES + hsum@W2 + b2 (sum_j A == 1 exactly), via 2KB LDS
//            bounce of hsum. No h_buf / A global round-trips.
// -------------------------------------------------------------------------
__global__ __launch_bounds__(256) void k_main(
    const float* __restrict__ s_buf, const float* __restrict__ t_buf,
    const float* __restrict__ EL, const float* __restrict__ UN,
    const float* __restrict__ ES, const float* __restrict__ W2,
    const float* __restrict__ b2,
    float* __restrict__ out, float* __restrict__ A_out)
{
    const int JT = 64;
    __shared__ float sj[JT][Dv];     // 32 KB (reused as hs[4][128] in phase 2)
    __shared__ float A_lds[4][Nv];   // 8 KB
    const int i0 = blockIdx.x * 4;
    const int b  = blockIdx.y;
    const int t  = threadIdx.x;

    // ---- phase 0: softmax((EL+g)/TAU) for rows i0..i0+3; wave w -> row w
    {
        const int w = t >> 6;        // wave id = relative row
        const int l = t & 63;
        const int i = i0 + w;
        float z[8], e[8];
        float m = -1e30f;
        #pragma unroll
        for (int m8 = 0; m8 < 8; ++m8) {
            const int c = l + 64*m8;
            const float u = UN[i*Nv + c];
            const float g = -logf(-logf(u + EPSv) + EPSv);
            z[m8] = (EL[i*Nv + c] + g) * 2.0f;   // 1/TAU = 2
            m = fmaxf(m, z[m8]);
        }
        #pragma unroll
        for (int off = 32; off >= 1; off >>= 1)
            m = fmaxf(m, __shfl_xor(m, off, 64));
        float ssum = 0.0f;
        #pragma unroll
        for (int m8 = 0; m8 < 8; ++m8) { e[m8] = expf(z[m8] - m); ssum += e[m8]; }
        #pragma unroll
        for (int off = 32; off >= 1; off >>= 1)
            ssum += __shfl_xor(ssum, off, 64);
        const float inv = 1.0f / ssum;
        #pragma unroll
        for (int m8 = 0; m8 < 8; ++m8) {
            const int c = l + 64*m8;
            const float a = e[m8] * inv;
            A_lds[w][c] = a;
            A_out[b*NN + i*Nv + c] = a;
        }
    }

    // ---- phase 1: weighted-relu aggregation
    const int d = t & 127;
    const int g = __builtin_amdgcn_readfirstlane(t >> 7);  // wave-uniform 0/1
    const int r0 = g*2;              // relative rows r0, r0+1
    const int ia = i0 + r0;
    const int ib = ia + 1;

    const float tv0 = t_buf[(b*Nv + ia)*Dv + d];
    const float tv1 = t_buf[(b*Nv + ib)*Dv + d];

    float acc0 = 0.0f, acc1 = 0.0f;
    for (int jt = 0; jt < Nv; jt += JT) {
        __syncthreads();             // also covers A_lds readiness on iter 0
        const float4* __restrict__ src = (const float4*)(s_buf + (b*Nv + jt)*Dv);
        float4* dst = (float4*)(&sj[0][0]);
        #pragma unroll
        for (int u = 0; u < 8; ++u)
            dst[t + u*256] = src[t + u*256];
        __syncthreads();
        #pragma unroll 4
        for (int j = 0; j < JT; ++j) {
            const float a0 = A_lds[r0][jt + j];     // broadcast; x4 -> b128
            const float a1 = A_lds[r0+1][jt + j];
            const float sv = sj[j][d];
            acc0 = fmaf(a0, fmaxf(sv + tv0, 0.0f), acc0);
            acc1 = fmaf(a1, fmaxf(sv + tv1, 0.0f), acc1);
        }
    }

    // ---- phase 2: out = ES + hsum@W2 + b2
    __syncthreads();                 // all sj reads done
    sj[r0][d]   = acc0;              // hsum rows 0..3 in sj[0..3][*]
    sj[r0+1][d] = acc1;
    __syncthreads();

    const int c  = t & 127;
    const int rg = t >> 7;           // rows rg*2, rg*2+1
    float o0 = b2[c], o1 = b2[c];
    #pragma unroll 8
    for (int k = 0; k < Dv; ++k) {
        const float w2 = W2[k*Dv + c];
        o0 = fmaf(sj[rg*2][k],   w2, o0);
        o1 = fmaf(sj[rg*2+1][k], w2, o1);
    }
    const int ro0 = (b*Nv + i0 + rg*2)*Dv + c;
    const int ro1 = ro0 + Dv;
    out[ro0] = ES[ro0] + o0;
    out[ro1] = ES[ro1] + o1;
}

extern "C" void kernel_launch(void* const* d_in, const int* in_sizes, int n_in,
                              void* d_out, int out_size, void* d_ws, size_t ws_size,
                              hipStream_t stream) {
    (void)in_sizes; (void)n_in; (void)out_size; (void)ws_size;
    const float* ES = (const float*)d_in[0];
    const float* Wp = (const float*)d_in[1];
    const float* bp = (const float*)d_in[2];
    const float* EL = (const float*)d_in[3];
    const float* W1 = (const float*)d_in[4];
    const float* b1 = (const float*)d_in[5];
    const float* W2 = (const float*)d_in[6];
    const float* b2 = (const float*)d_in[7];
    const float* UN = (const float*)d_in[8];

    float* out   = (float*)d_out;
    float* A_out = out + BND;            // A broadcast region: B*N*N floats

    float* s_buf = (float*)d_ws;         // s' = proj@W1_src + b1  (B*N*D)
    float* t_buf = s_buf + BND;          // t  = proj@W1_tgt       (B*N*D)

    k_prep<<<(Bv*Nv)/8, 256, 0, stream>>>(ES, Wp, bp, W1, b1, s_buf, t_buf);
    k_main<<<dim3(Nv/4, Bv), 256, 0, stream>>>(s_buf, t_buf, EL, UN, ES, W2, b2,
                                               out, A_out);
}